// Round 6
// baseline (1072.600 us; speedup 1.0000x reference)
//
#include <hip/hip_runtime.h>

#define S_LEN 2048
#define NB 2
#define NH 32
#define NKV 8
#define HD 128
#define HID 4096
#define NQKV 6144

using bf16x8 = __attribute__((ext_vector_type(8))) __bf16;
using f32x4  = __attribute__((ext_vector_type(4))) float;

__device__ __forceinline__ ushort f2b(float f) {
  uint u = __builtin_bit_cast(uint, f);
  u += 0x7fffu + ((u >> 16) & 1u);
  return (ushort)(u >> 16);
}
__device__ __forceinline__ float b2f(ushort h) {
  uint u = ((uint)h) << 16;
  return __builtin_bit_cast(float, u);
}

__device__ __forceinline__ uint cvt_pk_bf16(float lo, float hi) {
  uint r;
  asm("v_cvt_pk_bf16_f32 %0, %1, %2" : "=v"(r) : "v"(lo), "v"(hi));
  return r;
}

__device__ __forceinline__ void gld16(const void* g, void* l) {
  __builtin_amdgcn_global_load_lds((const __attribute__((address_space(1))) void*)g,
                                   (__attribute__((address_space(3))) void*)l, 16, 0, 0);
}

__device__ __forceinline__ void stc(float* C, size_t i, float v)  { C[i] = v; }
__device__ __forceinline__ void stc(ushort* C, size_t i, float v) { C[i] = f2b(v); }

// ---------------- f32 -> bf16 elementwise ----------------
__global__ void cvt_bf16(const float* __restrict__ src, ushort* __restrict__ dst, int n) {
  int i = (blockIdx.x * 256 + threadIdx.x) * 4;
  if (i < n) {
    float4 v = *(const float4*)(src + i);
    *(ushort4*)(dst + i) = make_ushort4(f2b(v.x), f2b(v.y), f2b(v.z), f2b(v.w));
  }
}

// ---------------- f32 [R][C] -> bf16 [C][R] transpose (padded tile, conflict-free) ----
__global__ void trans_f32_bf16(const float* __restrict__ src, ushort* __restrict__ dst,
                               int R, int C) {
  __shared__ float tile[32][33];
  const int c0 = blockIdx.x * 32, r0 = blockIdx.y * 32;
  const int x = threadIdx.x, y = threadIdx.y;  // block (32,8)
#pragma unroll
  for (int i = 0; i < 32; i += 8)
    tile[y + i][x] = src[(size_t)(r0 + y + i) * C + (c0 + x)];
  __syncthreads();
#pragma unroll
  for (int i = 0; i < 32; i += 8)
    dst[(size_t)(c0 + y + i) * R + (r0 + x)] = f2b(tile[x][y + i]);
}

// ================= pipelined 128x128 bf16 NT GEMM (ring-2, BK=64) =================
// (unchanged from passing R5 — stage i+1 at top, gate vmcnt(8), raw barriers,
//  conflict-free chunk-XOR swizzle both sides)
__device__ __forceinline__ void stage_tile(const ushort* __restrict__ A,
                                           const ushort* __restrict__ Bt,
                                           int lda, int ldb, int m0, int n0, int kt,
                                           ushort* dA, ushort* dB, int wave, int lane) {
#pragma unroll
  for (int h = 0; h < 4; ++h) {
    const int cb = h * 256 + wave * 64;  // wave-uniform LDS chunk base
    const int c = cb + lane;
    const int row = c >> 3;
    const int kc = (c & 7) ^ (row & 7);  // inverse-swizzled global k-chunk
    gld16(A  + (size_t)(m0 + row) * lda + kt + kc * 8, dA + cb * 8);
    gld16(Bt + (size_t)(n0 + row) * ldb + kt + kc * 8, dB + cb * 8);
  }
}

template <typename OutT>
__global__ __launch_bounds__(256, 2) void gemm_p2(const ushort* __restrict__ A,
                                                  const ushort* __restrict__ Bt,
                                                  OutT* __restrict__ C,
                                                  int M, int Ncol, int K,
                                                  int lda, int ldb) {
  __shared__ ushort As[2][128 * 64];
  __shared__ ushort Bs[2][128 * 64];
  const int tid = threadIdx.x, wave = tid >> 6, lane = tid & 63;
  const int lr = lane & 15, lg = lane >> 4;
  const int wm = wave >> 1, wn = wave & 1;
  const int m0 = blockIdx.y * 128, n0 = blockIdx.x * 128;

  f32x4 acc[4][4];
#pragma unroll
  for (int i = 0; i < 4; ++i)
#pragma unroll
    for (int j = 0; j < 4; ++j) acc[i][j] = (f32x4){0.f, 0.f, 0.f, 0.f};

  const int NT = K >> 6;

  stage_tile(A, Bt, lda, ldb, m0, n0, 0, As[0], Bs[0], wave, lane);

  for (int it = 0; it < NT; ++it) {
    const int buf = it & 1;
    if (it + 1 < NT) {
      stage_tile(A, Bt, lda, ldb, m0, n0, (it + 1) << 6, As[buf ^ 1], Bs[buf ^ 1],
                 wave, lane);
      asm volatile("s_waitcnt vmcnt(8)" ::: "memory");
    } else {
      asm volatile("s_waitcnt vmcnt(0)" ::: "memory");
    }
    asm volatile("s_barrier" ::: "memory");  // tile it resident, wave-global

#pragma unroll
    for (int kk = 0; kk < 2; ++kk) {  // two 32-K steps of the 64-K tile
      bf16x8 af[4], bfr[4];
#pragma unroll
      for (int f = 0; f < 4; ++f) {
        const int row = wm * 64 + f * 16 + lr;
        af[f] = *(const bf16x8*)(&As[buf][row * 64 + (((kk * 4 + lg) ^ (lr & 7)) << 3)]);
      }
#pragma unroll
      for (int g = 0; g < 4; ++g) {
        const int row = wn * 64 + g * 16 + lr;
        bfr[g] = *(const bf16x8*)(&Bs[buf][row * 64 + (((kk * 4 + lg) ^ (lr & 7)) << 3)]);
      }
      __builtin_amdgcn_s_setprio(1);
#pragma unroll
      for (int f = 0; f < 4; ++f)
#pragma unroll
        for (int g = 0; g < 4; ++g)
          acc[f][g] = __builtin_amdgcn_mfma_f32_16x16x32_bf16(af[f], bfr[g], acc[f][g], 0, 0, 0);
      __builtin_amdgcn_s_setprio(0);
    }
    asm volatile("s_barrier" ::: "memory");
  }

#pragma unroll
  for (int f = 0; f < 4; ++f)
#pragma unroll
    for (int g = 0; g < 4; ++g)
#pragma unroll
      for (int r = 0; r < 4; ++r) {
        const int row = m0 + wm * 64 + f * 16 + lg * 4 + r;
        const int col = n0 + wn * 64 + g * 16 + lr;
        stc(C, (size_t)row * Ncol + col, acc[f][g][r]);
      }
}

// ---------------- RoPE in-place on q/k heads of qkv (bf16) ----------------
__global__ __launch_bounds__(256) void rope_qk(ushort* __restrict__ qkv) {
  int t = blockIdx.x * 256 + threadIdx.x;
  const int i = t & 63;
  t >>= 6;
  const int head  = t % (NH + NKV);
  const int token = t / (NH + NKV);
  const int s = token & (S_LEN - 1);
  const size_t base = (size_t)token * NQKV + (head < NH ? head * HD : HID + (head - NH) * HD);
  const float x1 = b2f(qkv[base + i]);
  const float x2 = b2f(qkv[base + 64 + i]);
  const float invf = exp2f(-(float)i * 0.2076205059304602f);  // 10000^(-i/64)
  const float fr = (float)s * invf;
  float cs, sn;
  sincosf(fr, &sn, &cs);  // sincosf writes SIN first, COS second
  float o1 = x1 * cs - x2 * sn;
  float o2 = x2 * cs + x1 * sn;
  if (head < NH) {
    o1 *= 0.08838834764831845f;  // 1/sqrt(128) pre-applied to Q
    o2 *= 0.08838834764831845f;
  }
  qkv[base + i]      = f2b(o1);
  qkv[base + 64 + i] = f2b(o2);
}

// ---------------- V: qkv[token][5120+kv*128+d] -> Vt[b*8+kv][d][s] ----------------
__global__ void vtrans(const ushort* __restrict__ qkv, ushort* __restrict__ Vt) {
  __shared__ ushort tile[32][33];
  const int dt = blockIdx.x * 32, st = blockIdx.y * 32, bk = blockIdx.z;
  const int b = bk >> 3, kv = bk & 7;
  const int x = threadIdx.x, y = threadIdx.y;  // (32,8)
#pragma unroll
  for (int i = 0; i < 32; i += 8)
    tile[y + i][x] =
        qkv[(size_t)(b * S_LEN + st + y + i) * NQKV + 5120 + kv * HD + dt + x];
  __syncthreads();
#pragma unroll
  for (int i = 0; i < 32; i += 8)
    Vt[((size_t)bk * HD + dt + y + i) * S_LEN + st + x] = tile[x][y + i];
}

// ---------------- flash attention v4: 16-row wave tasks ----------------
// Doubling TLP vs v3: each wave owns 16 q rows (one MFMA M-tile); pairing over
// 128 16-row tiles {j, 127-j} keeps every wave at exactly 65 k-tiles. Grid =
// 1024 blocks x 4 waves = 16 waves/CU = 4 waves/SIMD (launch_bounds caps VGPR
// at 128). Same swapped-QK^T lane-local softmax, defer-max, per-lane li,
// hoisted K-then-V loads, per-wave private P tile (no barriers anywhere).
__global__ __launch_bounds__(256, 4) void attn_fa(ushort* __restrict__ qkv,
                                                  const ushort* __restrict__ Vt) {
  // XCD-contiguous swizzle: 1024 blocks, 128 consecutive per XCD => each XCD's
  // L2 touches ~2 (b,kvh) K/V working sets (~2 MB).
  const int lin = blockIdx.x + 64 * blockIdx.y + 512 * blockIdx.z;
  const int swz = (lin & 7) * 128 + (lin >> 3);
  const int qp = swz & 63;   // pair slot
  const int g  = swz >> 6;
  const int kvh = g & 7;
  const int b   = g >> 3;

  const int wid  = threadIdx.x >> 6;
  const int lane = threadIdx.x & 63;
  const int lr = lane & 15, lg = lane >> 4;
  const int h  = kvh * 4 + wid;

  const ushort* K = qkv + (size_t)(b * S_LEN) * NQKV + HID + kvh * HD;
  const ushort* V = Vt + (size_t)(b * NKV + kvh) * (HD * S_LEN);

  __shared__ ushort P[4][16 * 40];  // [wave][row][k padded 32->40]

  for (int seg = 0; seg < 2; ++seg) {
    const int qt = seg ? (127 - qp) : qp;  // 16-row tile index 0..127
    const int q0 = qt * 16;
    const ushort* Q = qkv + (size_t)(b * S_LEN + q0) * NQKV + h * HD;

    // Q fragments: qf[kb] = Q[lr][kb*32 + lg*8 .. +7]
    bf16x8 qf[4];
#pragma unroll
    for (int kb = 0; kb < 4; ++kb)
      qf[kb] = *(const bf16x8*)(Q + (size_t)lr * NQKV + kb * 32 + lg * 8);

    f32x4 o[8];
#pragma unroll
    for (int c = 0; c < 8; ++c) o[c] = (f32x4){0.f, 0.f, 0.f, 0.f};
    float mi = -1e30f, lip = 0.f;

    for (int k0 = 0; k0 <= q0 + 15; k0 += 32) {
      // hoisted loads: K first (QK consumes), V second (in flight thru softmax)
      bf16x8 kf[2][4];
#pragma unroll
      for (int kb = 0; kb < 4; ++kb) {
        kf[0][kb] = *(const bf16x8*)(K + (size_t)(k0 + lr) * NQKV + kb * 32 + lg * 8);
        kf[1][kb] = *(const bf16x8*)(K + (size_t)(k0 + 16 + lr) * NQKV + kb * 32 + lg * 8);
      }
      bf16x8 vf[8];
#pragma unroll
      for (int c = 0; c < 8; ++c)
        vf[c] = *(const bf16x8*)(V + (size_t)(c * 16 + lr) * S_LEN + k0 + lg * 8);

      // S^T[k][q] = mfma(K,Q): col(lr)=q, row(lg*4+r)=k within half u
      f32x4 s[2];
      s[0] = (f32x4){0.f, 0.f, 0.f, 0.f};
      s[1] = (f32x4){0.f, 0.f, 0.f, 0.f};
      __builtin_amdgcn_s_setprio(1);
#pragma unroll
      for (int kb = 0; kb < 4; ++kb) {
        s[0] = __builtin_amdgcn_mfma_f32_16x16x32_bf16(kf[0][kb], qf[kb], s[0], 0, 0, 0);
        s[1] = __builtin_amdgcn_mfma_f32_16x16x32_bf16(kf[1][kb], qf[kb], s[1], 0, 0, 0);
      }
      __builtin_amdgcn_s_setprio(0);

      if (k0 + 32 > q0) {  // causal mask: only the last k-tile needs it
#pragma unroll
        for (int u = 0; u < 2; ++u)
#pragma unroll
          for (int r = 0; r < 4; ++r)
            if (k0 + u * 16 + lg * 4 + r > q0 + lr) s[u][r] = -1e30f;
      }

      // lane-local tile max (no cross-lane ops in steady state)
      float pm = fmaxf(fmaxf(fmaxf(s[0][0], s[0][1]), fmaxf(s[0][2], s[0][3])),
                       fmaxf(fmaxf(s[1][0], s[1][1]), fmaxf(s[1][2], s[1][3])));

      // defer-max: full reduce + rescale only when lane-local max grew past mi+8
      if (__any(pm > mi + 8.f)) {
        float m = pm;
        m = fmaxf(m, __shfl_xor(m, 16));
        m = fmaxf(m, __shfl_xor(m, 32));
        const float mn = fmaxf(mi, m);
        const float al = __expf(mi - mn);
        mi = mn;
        lip *= al;
#pragma unroll
        for (int r = 0; r < 4; ++r) {
          const float ar = __shfl(al, lg * 4 + r);  // o rows are q=lg*4+r
#pragma unroll
          for (int c = 0; c < 8; ++c) o[c][r] *= ar;
        }
      }

      float p[2][4];
#pragma unroll
      for (int u = 0; u < 2; ++u)
#pragma unroll
        for (int r = 0; r < 4; ++r) p[u][r] = __expf(s[u][r] - mi);
      lip += ((p[0][0] + p[0][1]) + (p[0][2] + p[0][3])) +
             ((p[1][0] + p[1][1]) + (p[1][2] + p[1][3]));
      ushort* Pw = &P[wid][0];
#pragma unroll
      for (int u = 0; u < 2; ++u) {
        const uint w0 = cvt_pk_bf16(p[u][0], p[u][1]);
        const uint w1 = cvt_pk_bf16(p[u][2], p[u][3]);
        *(uint2*)(Pw + lr * 40 + u * 16 + lg * 4) = make_uint2(w0, w1);
      }
      // A-fragment of P: row=lr, k=lg*8..+7 (in-wave LDS transpose, no barrier)
      const bf16x8 pa = *(const bf16x8*)(Pw + lr * 40 + lg * 8);

      __builtin_amdgcn_s_setprio(1);
#pragma unroll
      for (int c = 0; c < 8; ++c)
        o[c] = __builtin_amdgcn_mfma_f32_16x16x32_bf16(pa, vf[c], o[c], 0, 0, 0);
      __builtin_amdgcn_s_setprio(0);
    }

    // one cross-lane li reduction per segment
    float rt = lip;
    rt += __shfl_xor(rt, 16);
    rt += __shfl_xor(rt, 32);
    const float linv = 1.f / rt;
#pragma unroll
    for (int r = 0; r < 4; ++r) {
      const float ir = __shfl(linv, lg * 4 + r);
      const size_t row = (size_t)(b * S_LEN + q0 + lg * 4 + r) * NQKV + h * HD;
#pragma unroll
      for (int c = 0; c < 8; ++c) qkv[row + c * 16 + lr] = f2b(o[c][r] * ir);
    }
  }
}

extern "C" void kernel_launch(void* const* d_in, const int* in_sizes, int n_in,
                              void* d_out, int out_size, void* d_ws, size_t ws_size,
                              hipStream_t stream) {
  const float* hidden = (const float*)d_in[1];
  const float* w_qkv  = (const float*)d_in[2];
  const float* w_o    = (const float*)d_in[3];
  float* out = (float*)d_out;
  char* ws = (char*)d_ws;

  // workspace layout (128 MiB):
  // R0 [0, 48 MiB)   : wqkvT bf16 [6144][4096]; after gemm1: Vt bf16 [16][128][2048]
  // R1 [48, 80 MiB)  : hb bf16 [4096][4096];    after gemm1: woT bf16 [4096][4096]
  // R2 [80, 128 MiB) : qkv bf16 [4096][6144]; rope in-place; attn into q slots
  ushort* wqkvT = (ushort*)(ws);
  ushort* Vt    = (ushort*)(ws);
  ushort* hb    = (ushort*)(ws + (48u << 20));
  ushort* woT   = (ushort*)(ws + (48u << 20));
  ushort* qkvb  = (ushort*)(ws + (80u << 20));

  // 1) weight + activation prep
  trans_f32_bf16<<<dim3(192, 128), dim3(32, 8), 0, stream>>>(w_qkv, wqkvT, HID, NQKV);
  cvt_bf16<<<16384, 256, 0, stream>>>(hidden, hb, NB * S_LEN * HID);
  // 2) qkv = hb @ wqkvT^T  (ring-2 BK=64 pipelined 128x128)
  gemm_p2<ushort><<<dim3(48, 32), 256, 0, stream>>>(
      hb, wqkvT, qkvb, NB * S_LEN, NQKV, HID, HID, HID);
  // 3) RoPE in-place (q pre-scaled by 1/sqrt(D))
  rope_qk<<<40960, 256, 0, stream>>>(qkvb);
  // 4) V -> Vt[d][s]  (into dead wqkvT region)
  vtrans<<<dim3(4, 64, 16), dim3(32, 8), 0, stream>>>(qkvb, Vt);
  // 5) w_o -> woT (into dead hb region)
  trans_f32_bf16<<<dim3(128, 128), dim3(32, 8), 0, stream>>>(w_o, woT, HID, HID);
  // 6) flash attention v4: 16-row wave tasks, 1024 equal-work blocks
  attn_fa<<<dim3(64, 8, 2), 256, 0, stream>>>(qkvb, Vt);
  // 7) out = attn @ woT^T  (ring-2 BK=64 pipelined 128x128)
  gemm_p2<float><<<dim3(32, 32), 256, 0, stream>>>(
      qkvb, woT, out, NB * S_LEN, HID, HID, NQKV, HID);
}

// Round 7
// 789.405 us; speedup vs baseline: 1.3587x; 1.3587x over previous
//
#include <hip/hip_runtime.h>

#define S_LEN 2048
#define NB 2
#define NH 32
#define NKV 8
#define HD 128
#define HID 4096
#define NQKV 6144

using bf16x8 = __attribute__((ext_vector_type(8))) __bf16;
using f32x4  = __attribute__((ext_vector_type(4))) float;

__device__ __forceinline__ ushort f2b(float f) {
  uint u = __builtin_bit_cast(uint, f);
  u += 0x7fffu + ((u >> 16) & 1u);
  return (ushort)(u >> 16);
}
__device__ __forceinline__ float b2f(ushort h) {
  uint u = ((uint)h) << 16;
  return __builtin_bit_cast(float, u);
}

__device__ __forceinline__ uint cvt_pk_bf16(float lo, float hi) {
  uint r;
  asm("v_cvt_pk_bf16_f32 %0, %1, %2" : "=v"(r) : "v"(lo), "v"(hi));
  return r;
}

__device__ __forceinline__ void gld16(const void* g, void* l) {
  __builtin_amdgcn_global_load_lds((const __attribute__((address_space(1))) void*)g,
                                   (__attribute__((address_space(3))) void*)l, 16, 0, 0);
}

__device__ __forceinline__ void stc(float* C, size_t i, float v)  { C[i] = v; }
__device__ __forceinline__ void stc(ushort* C, size_t i, float v) { C[i] = f2b(v); }

// ---------------- f32 -> bf16 elementwise ----------------
__global__ void cvt_bf16(const float* __restrict__ src, ushort* __restrict__ dst, int n) {
  int i = (blockIdx.x * 256 + threadIdx.x) * 4;
  if (i < n) {
    float4 v = *(const float4*)(src + i);
    *(ushort4*)(dst + i) = make_ushort4(f2b(v.x), f2b(v.y), f2b(v.z), f2b(v.w));
  }
}

// ---------------- f32 [R][C] -> bf16 [C][R] transpose (padded tile, conflict-free) ----
__global__ void trans_f32_bf16(const float* __restrict__ src, ushort* __restrict__ dst,
                               int R, int C) {
  __shared__ float tile[32][33];
  const int c0 = blockIdx.x * 32, r0 = blockIdx.y * 32;
  const int x = threadIdx.x, y = threadIdx.y;  // block (32,8)
#pragma unroll
  for (int i = 0; i < 32; i += 8)
    tile[y + i][x] = src[(size_t)(r0 + y + i) * C + (c0 + x)];
  __syncthreads();
#pragma unroll
  for (int i = 0; i < 32; i += 8)
    dst[(size_t)(c0 + y + i) * R + (r0 + x)] = f2b(tile[x][y + i]);
}

// ================= pipelined 128x128 bf16 NT GEMM (ring-2, BK=64) =================
// (unchanged from passing R5)
__device__ __forceinline__ void stage_tile(const ushort* __restrict__ A,
                                           const ushort* __restrict__ Bt,
                                           int lda, int ldb, int m0, int n0, int kt,
                                           ushort* dA, ushort* dB, int wave, int lane) {
#pragma unroll
  for (int h = 0; h < 4; ++h) {
    const int cb = h * 256 + wave * 64;  // wave-uniform LDS chunk base
    const int c = cb + lane;
    const int row = c >> 3;
    const int kc = (c & 7) ^ (row & 7);  // inverse-swizzled global k-chunk
    gld16(A  + (size_t)(m0 + row) * lda + kt + kc * 8, dA + cb * 8);
    gld16(Bt + (size_t)(n0 + row) * ldb + kt + kc * 8, dB + cb * 8);
  }
}

template <typename OutT>
__global__ __launch_bounds__(256, 2) void gemm_p2(const ushort* __restrict__ A,
                                                  const ushort* __restrict__ Bt,
                                                  OutT* __restrict__ C,
                                                  int M, int Ncol, int K,
                                                  int lda, int ldb) {
  __shared__ ushort As[2][128 * 64];
  __shared__ ushort Bs[2][128 * 64];
  const int tid = threadIdx.x, wave = tid >> 6, lane = tid & 63;
  const int lr = lane & 15, lg = lane >> 4;
  const int wm = wave >> 1, wn = wave & 1;
  const int m0 = blockIdx.y * 128, n0 = blockIdx.x * 128;

  f32x4 acc[4][4];
#pragma unroll
  for (int i = 0; i < 4; ++i)
#pragma unroll
    for (int j = 0; j < 4; ++j) acc[i][j] = (f32x4){0.f, 0.f, 0.f, 0.f};

  const int NT = K >> 6;

  stage_tile(A, Bt, lda, ldb, m0, n0, 0, As[0], Bs[0], wave, lane);

  for (int it = 0; it < NT; ++it) {
    const int buf = it & 1;
    if (it + 1 < NT) {
      stage_tile(A, Bt, lda, ldb, m0, n0, (it + 1) << 6, As[buf ^ 1], Bs[buf ^ 1],
                 wave, lane);
      asm volatile("s_waitcnt vmcnt(8)" ::: "memory");
    } else {
      asm volatile("s_waitcnt vmcnt(0)" ::: "memory");
    }
    asm volatile("s_barrier" ::: "memory");  // tile it resident, wave-global

#pragma unroll
    for (int kk = 0; kk < 2; ++kk) {  // two 32-K steps of the 64-K tile
      bf16x8 af[4], bfr[4];
#pragma unroll
      for (int f = 0; f < 4; ++f) {
        const int row = wm * 64 + f * 16 + lr;
        af[f] = *(const bf16x8*)(&As[buf][row * 64 + (((kk * 4 + lg) ^ (lr & 7)) << 3)]);
      }
#pragma unroll
      for (int g = 0; g < 4; ++g) {
        const int row = wn * 64 + g * 16 + lr;
        bfr[g] = *(const bf16x8*)(&Bs[buf][row * 64 + (((kk * 4 + lg) ^ (lr & 7)) << 3)]);
      }
      __builtin_amdgcn_s_setprio(1);
#pragma unroll
      for (int f = 0; f < 4; ++f)
#pragma unroll
        for (int g = 0; g < 4; ++g)
          acc[f][g] = __builtin_amdgcn_mfma_f32_16x16x32_bf16(af[f], bfr[g], acc[f][g], 0, 0, 0);
      __builtin_amdgcn_s_setprio(0);
    }
    asm volatile("s_barrier" ::: "memory");
  }

#pragma unroll
  for (int f = 0; f < 4; ++f)
#pragma unroll
    for (int g = 0; g < 4; ++g)
#pragma unroll
      for (int r = 0; r < 4; ++r) {
        const int row = m0 + wm * 64 + f * 16 + lg * 4 + r;
        const int col = n0 + wn * 64 + g * 16 + lr;
        stc(C, (size_t)row * Ncol + col, acc[f][g][r]);
      }
}

// ---------------- RoPE in-place on q/k heads of qkv (bf16) ----------------
__global__ __launch_bounds__(256) void rope_qk(ushort* __restrict__ qkv) {
  int t = blockIdx.x * 256 + threadIdx.x;
  const int i = t & 63;
  t >>= 6;
  const int head  = t % (NH + NKV);
  const int token = t / (NH + NKV);
  const int s = token & (S_LEN - 1);
  const size_t base = (size_t)token * NQKV + (head < NH ? head * HD : HID + (head - NH) * HD);
  const float x1 = b2f(qkv[base + i]);
  const float x2 = b2f(qkv[base + 64 + i]);
  const float invf = exp2f(-(float)i * 0.2076205059304602f);  // 10000^(-i/64)
  const float fr = (float)s * invf;
  float cs, sn;
  sincosf(fr, &sn, &cs);  // sincosf writes SIN first, COS second
  float o1 = x1 * cs - x2 * sn;
  float o2 = x2 * cs + x1 * sn;
  if (head < NH) {
    o1 *= 0.08838834764831845f;  // 1/sqrt(128) pre-applied to Q
    o2 *= 0.08838834764831845f;
  }
  qkv[base + i]      = f2b(o1);
  qkv[base + 64 + i] = f2b(o2);
}

// ---------------- V: qkv[token][5120+kv*128+d] -> Vt[b*8+kv][d][s] ----------------
__global__ void vtrans(const ushort* __restrict__ qkv, ushort* __restrict__ Vt) {
  __shared__ ushort tile[32][33];
  const int dt = blockIdx.x * 32, st = blockIdx.y * 32, bk = blockIdx.z;
  const int b = bk >> 3, kv = bk & 7;
  const int x = threadIdx.x, y = threadIdx.y;  // (32,8)
#pragma unroll
  for (int i = 0; i < 32; i += 8)
    tile[y + i][x] =
        qkv[(size_t)(b * S_LEN + st + y + i) * NQKV + 5120 + kv * HD + dt + x];
  __syncthreads();
#pragma unroll
  for (int i = 0; i < 32; i += 8)
    Vt[((size_t)bk * HD + dt + y + i) * S_LEN + st + x] = tile[x][y + i];
}

// ---------------- flash attention v5: v3 structure + block-shared LDS K/V ----------------
// 32 q-rows/wave, pairing {qp, 63-qp} (65 k-tiles/wave, 512 equal blocks).
// NEW vs v3 (R5, 257us): the 4 waves of a block share one kvh => K-tile and
// V-tile staged ONCE per block into LDS via global_load_lds, double-buffered
// with the gemm_p2-proven schedule {stage i+1 -> vmcnt(4) -> barrier ->
// compute -> barrier}. Cuts VMEM instrs 4x (24 -> 4 per wave per tile) and
// removes the K/V register pressure that forced load serialization (R6 lesson).
// LDS swizzles (both-sides, rule #21):
//   Ks[32 rows][16 chunks]: slot = c ^ (row&15)      (reads 2-way = free)
//   Vs[128 rows][4 chunks]: slot = c ^ ((row>>1)&3)  (fixes 8-way of linear)
__global__ __launch_bounds__(256) void attn_fa(ushort* __restrict__ qkv,
                                               const ushort* __restrict__ Vt) {
  const int lin = blockIdx.x + 32 * blockIdx.y + 256 * blockIdx.z;
  const int swz = (lin & 7) * 64 + (lin >> 3);
  const int qp = swz & 31;
  const int g  = swz >> 5;
  const int kvh = g & 7;
  const int b   = g >> 3;

  const int wid  = threadIdx.x >> 6;
  const int lane = threadIdx.x & 63;
  const int lr = lane & 15, lg = lane >> 4;
  const int h  = kvh * 4 + wid;

  const ushort* K = qkv + (size_t)(b * S_LEN) * NQKV + HID + kvh * HD;
  const ushort* V = Vt + (size_t)(b * NKV + kvh) * (HD * S_LEN);

  __shared__ ushort Ks[2][32 * 128];   // 8 KB per buf
  __shared__ ushort Vs[2][128 * 32];   // 8 KB per buf
  __shared__ ushort P[4][16 * 40];     // per-wave private P tile

  for (int seg = 0; seg < 2; ++seg) {
    const int qt = seg ? (63 - qp) : qp;
    const int q0 = qt * 32;
    const ushort* Q = qkv + (size_t)(b * S_LEN + q0) * NQKV + h * HD;

    bf16x8 qf[2][4];
#pragma unroll
    for (int t = 0; t < 2; ++t)
#pragma unroll
      for (int kb = 0; kb < 4; ++kb)
        qf[t][kb] = *(const bf16x8*)(Q + (size_t)(t * 16 + lr) * NQKV + kb * 32 + lg * 8);

    f32x4 o[2][8];
#pragma unroll
    for (int t = 0; t < 2; ++t)
#pragma unroll
      for (int c = 0; c < 8; ++c) o[t][c] = (f32x4){0.f, 0.f, 0.f, 0.f};
    float mi[2]  = {-1e30f, -1e30f};
    float lip[2] = {0.f, 0.f};

    const int NTk = qt + 1;  // uniform across the block

    // prologue: stage tile 0 (4 gld16/wave: 2 K + 2 V)
#pragma unroll
    for (int it = 0; it < 2; ++it) {
      const int cb = it * 256 + wid * 64;
      const int d = cb + lane;
      const int krow = d >> 4, kslot = d & 15;
      gld16(K + (size_t)krow * NQKV + ((kslot ^ (krow & 15)) * 8), &Ks[0][cb * 8]);
      const int vrow = d >> 2, vslot = d & 3;
      gld16(V + (size_t)vrow * S_LEN + ((vslot ^ ((vrow >> 1) & 3)) * 8), &Vs[0][cb * 8]);
    }

    for (int itk = 0; itk < NTk; ++itk) {
      const int k0 = itk << 5;
      const int bufi = itk & 1;
      if (itk + 1 < NTk) {
        const int kn = k0 + 32;
#pragma unroll
        for (int it = 0; it < 2; ++it) {
          const int cb = it * 256 + wid * 64;
          const int d = cb + lane;
          const int krow = d >> 4, kslot = d & 15;
          gld16(K + (size_t)(kn + krow) * NQKV + ((kslot ^ (krow & 15)) * 8),
                &Ks[bufi ^ 1][cb * 8]);
          const int vrow = d >> 2, vslot = d & 3;
          gld16(V + (size_t)vrow * S_LEN + kn + ((vslot ^ ((vrow >> 1) & 3)) * 8),
                &Vs[bufi ^ 1][cb * 8]);
        }
        asm volatile("s_waitcnt vmcnt(4)" ::: "memory");  // tile itk landed
      } else {
        asm volatile("s_waitcnt vmcnt(0)" ::: "memory");
      }
      asm volatile("s_barrier" ::: "memory");

      // K fragments from LDS: row = u*16+lr, slot = (kb*4+lg) ^ lr
      bf16x8 kf[2][4];
#pragma unroll
      for (int u = 0; u < 2; ++u)
#pragma unroll
        for (int kb = 0; kb < 4; ++kb)
          kf[u][kb] = *(const bf16x8*)(
              &Ks[bufi][(u * 16 + lr) * 128 + (((kb * 4 + lg) ^ lr) << 3)]);

      f32x4 s[2][2];
#pragma unroll
      for (int t = 0; t < 2; ++t)
#pragma unroll
        for (int u = 0; u < 2; ++u) s[t][u] = (f32x4){0.f, 0.f, 0.f, 0.f};

      __builtin_amdgcn_s_setprio(1);
#pragma unroll
      for (int kb = 0; kb < 4; ++kb) {
        s[0][0] = __builtin_amdgcn_mfma_f32_16x16x32_bf16(kf[0][kb], qf[0][kb], s[0][0], 0, 0, 0);
        s[1][0] = __builtin_amdgcn_mfma_f32_16x16x32_bf16(kf[0][kb], qf[1][kb], s[1][0], 0, 0, 0);
        s[0][1] = __builtin_amdgcn_mfma_f32_16x16x32_bf16(kf[1][kb], qf[0][kb], s[0][1], 0, 0, 0);
        s[1][1] = __builtin_amdgcn_mfma_f32_16x16x32_bf16(kf[1][kb], qf[1][kb], s[1][1], 0, 0, 0);
      }
      __builtin_amdgcn_s_setprio(0);

      if (k0 == q0) {  // causal mask, diagonal tile only
#pragma unroll
        for (int t = 0; t < 2; ++t)
#pragma unroll
          for (int u = 0; u < 2; ++u)
#pragma unroll
            for (int r = 0; r < 4; ++r)
              if (u * 16 + lg * 4 + r > t * 16 + lr) s[t][u][r] = -1e30f;
      }

      float pm[2];
#pragma unroll
      for (int t = 0; t < 2; ++t) {
        float a = fmaxf(fmaxf(s[t][0][0], s[t][0][1]), fmaxf(s[t][0][2], s[t][0][3]));
        float c = fmaxf(fmaxf(s[t][1][0], s[t][1][1]), fmaxf(s[t][1][2], s[t][1][3]));
        pm[t] = fmaxf(a, c);
      }

      if (__any((pm[0] > mi[0] + 8.f) || (pm[1] > mi[1] + 8.f))) {
#pragma unroll
        for (int t = 0; t < 2; ++t) {
          float m = pm[t];
          m = fmaxf(m, __shfl_xor(m, 16));
          m = fmaxf(m, __shfl_xor(m, 32));
          const float mn = fmaxf(mi[t], m);
          const float al = __expf(mi[t] - mn);
          mi[t] = mn;
          lip[t] *= al;
#pragma unroll
          for (int r = 0; r < 4; ++r) {
            const float ar = __shfl(al, lg * 4 + r);
#pragma unroll
            for (int c = 0; c < 8; ++c) o[t][c][r] *= ar;
          }
        }
      }

#pragma unroll
      for (int t = 0; t < 2; ++t) {
        float p[2][4];
#pragma unroll
        for (int u = 0; u < 2; ++u)
#pragma unroll
          for (int r = 0; r < 4; ++r) p[u][r] = __expf(s[t][u][r] - mi[t]);
        lip[t] += ((p[0][0] + p[0][1]) + (p[0][2] + p[0][3])) +
                  ((p[1][0] + p[1][1]) + (p[1][2] + p[1][3]));
#pragma unroll
        for (int u = 0; u < 2; ++u) {
          const uint w0 = cvt_pk_bf16(p[u][0], p[u][1]);
          const uint w1 = cvt_pk_bf16(p[u][2], p[u][3]);
          *(uint2*)(&P[wid][0] + lr * 40 + u * 16 + lg * 4) = make_uint2(w0, w1);
        }
        // A-fragment of P: row=lr, k=lg*8..+7 (in-wave LDS transpose, no barrier)
        const bf16x8 pa = *(const bf16x8*)(&P[wid][0] + lr * 40 + lg * 8);

        // V fragments from LDS: row = c*16+lr, slot = lg ^ ((lr>>1)&3)
        __builtin_amdgcn_s_setprio(1);
#pragma unroll
        for (int c = 0; c < 8; ++c) {
          const bf16x8 vf = *(const bf16x8*)(
              &Vs[bufi][(c * 16 + lr) * 32 + ((lg ^ ((lr >> 1) & 3)) << 3)]);
          o[t][c] = __builtin_amdgcn_mfma_f32_16x16x32_bf16(pa, vf, o[t][c], 0, 0, 0);
        }
        __builtin_amdgcn_s_setprio(0);
      }

      asm volatile("s_barrier" ::: "memory");  // all waves done reading bufi
    }

    float linv[2];
#pragma unroll
    for (int t = 0; t < 2; ++t) {
      float rt = lip[t];
      rt += __shfl_xor(rt, 16);
      rt += __shfl_xor(rt, 32);
      linv[t] = 1.f / rt;
    }
#pragma unroll
    for (int t = 0; t < 2; ++t) {
#pragma unroll
      for (int r = 0; r < 4; ++r) {
        const float ir = __shfl(linv[t], lg * 4 + r);
        const size_t row = (size_t)(b * S_LEN + q0 + t * 16 + lg * 4 + r) * NQKV + h * HD;
#pragma unroll
        for (int c = 0; c < 8; ++c) qkv[row + c * 16 + lr] = f2b(o[t][c][r] * ir);
      }
    }
  }
}

extern "C" void kernel_launch(void* const* d_in, const int* in_sizes, int n_in,
                              void* d_out, int out_size, void* d_ws, size_t ws_size,
                              hipStream_t stream) {
  const float* hidden = (const float*)d_in[1];
  const float* w_qkv  = (const float*)d_in[2];
  const float* w_o    = (const float*)d_in[3];
  float* out = (float*)d_out;
  char* ws = (char*)d_ws;

  // workspace layout (128 MiB):
  // R0 [0, 48 MiB)   : wqkvT bf16 [6144][4096]; after gemm1: Vt bf16 [16][128][2048]
  // R1 [48, 80 MiB)  : hb bf16 [4096][4096];    after gemm1: woT bf16 [4096][4096]
  // R2 [80, 128 MiB) : qkv bf16 [4096][6144]; rope in-place; attn into q slots
  ushort* wqkvT = (ushort*)(ws);
  ushort* Vt    = (ushort*)(ws);
  ushort* hb    = (ushort*)(ws + (48u << 20));
  ushort* woT   = (ushort*)(ws + (48u << 20));
  ushort* qkvb  = (ushort*)(ws + (80u << 20));

  // 1) weight + activation prep
  trans_f32_bf16<<<dim3(192, 128), dim3(32, 8), 0, stream>>>(w_qkv, wqkvT, HID, NQKV);
  cvt_bf16<<<16384, 256, 0, stream>>>(hidden, hb, NB * S_LEN * HID);
  // 2) qkv = hb @ wqkvT^T  (ring-2 BK=64 pipelined 128x128)
  gemm_p2<ushort><<<dim3(48, 32), 256, 0, stream>>>(
      hb, wqkvT, qkvb, NB * S_LEN, NQKV, HID, HID, HID);
  // 3) RoPE in-place (q pre-scaled by 1/sqrt(D))
  rope_qk<<<40960, 256, 0, stream>>>(qkvb);
  // 4) V -> Vt[d][s]  (into dead wqkvT region)
  vtrans<<<dim3(4, 64, 16), dim3(32, 8), 0, stream>>>(qkvb, Vt);
  // 5) w_o -> woT (into dead hb region)
  trans_f32_bf16<<<dim3(128, 128), dim3(32, 8), 0, stream>>>(w_o, woT, HID, HID);
  // 6) flash attention v5: paired q-tiles, block-shared LDS K/V double-buffer
  attn_fa<<<dim3(32, 8, 2), 256, 0, stream>>>(qkvb, Vt);
  // 7) out = attn @ woT^T  (ring-2 BK=64 pipelined 128x128)
  gemm_p2<float><<<dim3(32, 32), 256, 0, stream>>>(
      qkvb, woT, out, NB * S_LEN, HID, HID, NQKV, HID);
}